// Round 1
// baseline (415.714 us; speedup 1.0000x reference)
//
#include <hip/hip_runtime.h>

typedef __attribute__((ext_vector_type(8))) __bf16 bf16x8;
typedef __attribute__((ext_vector_type(4))) float f32x4;

#define N_ 1024
#define C_ 64
#define BP_ 48

static __device__ __forceinline__ unsigned short f2bf(float f) {
    __bf16 b = (__bf16)f;
    return __builtin_bit_cast(unsigned short, b);
}

// ---------------------------------------------------------------------------
// K1: v1/v2 fold of W_emb, s1/s2 per node, and bf16 transpose xT[bp][c][j].
// grid (16 j-tiles, 48 bp), block 256 (4 waves).
// ---------------------------------------------------------------------------
__global__ __launch_bounds__(256) void gat_pre(
    const float* __restrict__ x, const float* __restrict__ Wemb,
    const float* __restrict__ a1, const float* __restrict__ a2,
    float* __restrict__ s1g, float* __restrict__ s2g,
    unsigned short* __restrict__ xT)
{
    __shared__ float xs[64][65];
    const int t = threadIdx.x, l = t & 63, w = t >> 6;
    const int j0 = blockIdx.x * 64;
    const int bp = blockIdx.y;

    // v1[c]=sum_h a1[h]*W_emb[h][c] for c = lane (x_emb folds away)
    float v1 = 0.f, v2 = 0.f;
    #pragma unroll 8
    for (int h = 0; h < 64; ++h) {
        float we = Wemb[h * 64 + l];
        v1 = fmaf(a1[h], we, v1);
        v2 = fmaf(a2[h], we, v2);
    }
    const float* xb = x + ((size_t)bp * N_ + j0) * C_;
    #pragma unroll
    for (int it = 0; it < 16; ++it) {
        int j = it * 4 + w;                 // wave w handles rows w,4+w,...
        float xv = xb[j * C_ + l];          // coalesced 256B
        xs[j][l] = xv;
        float p1 = xv * v1, p2 = xv * v2;
        #pragma unroll
        for (int off = 32; off >= 1; off >>= 1) {
            p1 += __shfl_xor(p1, off);
            p2 += __shfl_xor(p2, off);
        }
        if (l == 0) {
            s1g[bp * N_ + j0 + j] = p1;
            s2g[bp * N_ + j0 + j] = p2;
        }
    }
    __syncthreads();
    // transpose out: thread t handles c = t>>2, 16 j's
    const int c = t >> 2, part = t & 3;
    unsigned int ow[8];
    #pragma unroll
    for (int k = 0; k < 16; k += 2) {
        unsigned int lo = f2bf(xs[part * 16 + k][c]);
        unsigned int hi = f2bf(xs[part * 16 + k + 1][c]);
        ow[k >> 1] = lo | (hi << 16);
    }
    uint4* dst = (uint4*)(xT + (size_t)bp * C_ * N_ + (size_t)c * N_ + j0 + part * 16);
    dst[0] = make_uint4(ow[0], ow[1], ow[2], ow[3]);
    dst[1] = make_uint4(ow[4], ow[5], ow[6], ow[7]);
}

// ---------------------------------------------------------------------------
// K2: fused masked-softmax attention + aggregation + output linear + sigmoid.
// grid (16 i-tiles, 48 bp), block 256 = 4 independent waves x 16 rows each.
// Online softmax; P->LDS bf16; MFMA 16x16x32 vs xT B-frags loaded from global.
// Also copies A to d_out (output[1]) while loading it for the mask.
// ---------------------------------------------------------------------------
__global__ __launch_bounds__(256) void gat_main(
    const float* __restrict__ Ag, const unsigned short* __restrict__ xT,
    const float* __restrict__ s1g, const float* __restrict__ s2g,
    const float* __restrict__ Wlin, float* __restrict__ out,
    float* __restrict__ outA)
{
    // per-wave P tile: 16 rows x 128 j bf16, row stride 136 ushort = 272B
    // (= 68 dwords = 4*17 -> b128 frag reads at the 8-dwords/bank optimum)
    __shared__ unsigned short Plds[4][16][136];
    const int l = threadIdx.x & 63, w = threadIdx.x >> 6;
    const int i15 = l & 15, q = l >> 4;
    const int bp = blockIdx.y;
    const int ibase = blockIdx.x * 64 + w * 16;

    const float* Arow = Ag + (size_t)bp * N_ * N_ + (size_t)ibase * N_;
    float* oArow = outA + (size_t)bp * N_ * N_ + (size_t)ibase * N_;
    const unsigned short* xTb = xT + (size_t)bp * C_ * N_;

    const float s1_l = s1g[bp * N_ + ibase + i15];  // lane rr holds s1 of row rr

    f32x4 acc[4] = {};                 // agg: rows q*4+r, c = nt*16+i15
    float m_keep[4] = {-1e30f, -1e30f, -1e30f, -1e30f};
    float l_keep[4] = {0.f, 0.f, 0.f, 0.f};
    float a_keep[4];

    for (int jc = 0; jc < 8; ++jc) {
        const int j0 = jc * 128;
        float2 s2p = *(const float2*)&s2g[bp * N_ + j0 + 2 * l];
        float2 Ap[16];
        #pragma unroll
        for (int rr = 0; rr < 16; ++rr)   // prefetch the HBM A stream
            Ap[rr] = *(const float2*)&Arow[(size_t)rr * N_ + j0 + 2 * l];
        #pragma unroll
        for (int rr = 0; rr < 16; ++rr) {
            *(float2*)&oArow[(size_t)rr * N_ + j0 + 2 * l] = Ap[rr];  // A passthrough
            float s1i = __shfl(s1_l, rr);
            float z0 = s1i + s2p.x; z0 = fmaxf(z0, 0.01f * z0);  // leaky_relu
            float z1 = s1i + s2p.y; z1 = fmaxf(z1, 0.01f * z1);
            bool msk0 = (Ap[rr].x != 0.f), msk1 = (Ap[rr].y != 0.f);
            float cm = fmaxf(msk0 ? z0 : -1e30f, msk1 ? z1 : -1e30f);
            #pragma unroll
            for (int off = 32; off >= 1; off >>= 1)
                cm = fmaxf(cm, __shfl_xor(cm, off));
            float mo = __shfl(m_keep[rr & 3], (rr >> 2) << 4);
            float mn = fmaxf(mo, cm);
            float al = __expf(mo - mn);
            float e0 = msk0 ? __expf(z0 - mn) : 0.f;  // explicit mask: no exp(NaN)
            float e1 = msk1 ? __expf(z1 - mn) : 0.f;
            float cs = e0 + e1;
            #pragma unroll
            for (int off = 32; off >= 1; off >>= 1)
                cs += __shfl_xor(cs, off);
            if (q == (rr >> 2)) {              // lane's quad owns rows q*4..q*4+3
                m_keep[rr & 3] = mn;
                l_keep[rr & 3] = l_keep[rr & 3] * al + cs;
                a_keep[rr & 3] = al;
            }
            ((unsigned int*)&Plds[w][rr][0])[l] =
                (unsigned int)f2bf(e0) | ((unsigned int)f2bf(e1) << 16);
        }
        // rescale accumulator by this chunk's alpha (flash update)
        #pragma unroll
        for (int nt = 0; nt < 4; ++nt) {
            acc[nt][0] *= a_keep[0]; acc[nt][1] *= a_keep[1];
            acc[nt][2] *= a_keep[2]; acc[nt][3] *= a_keep[3];
        }
        // acc += P_chunk @ X_chunk   (M16 x N64 x K128 per wave)
        #pragma unroll
        for (int s = 0; s < 4; ++s) {
            bf16x8 af = *(const bf16x8*)&Plds[w][i15][s * 32 + q * 8];
            #pragma unroll
            for (int nt = 0; nt < 4; ++nt) {
                bf16x8 bfr = *(const bf16x8*)&xTb[(size_t)(nt * 16 + i15) * N_ +
                                                  j0 + s * 32 + q * 8];
                acc[nt] = __builtin_amdgcn_mfma_f32_16x16x32_bf16(af, bfr, acc[nt], 0, 0, 0);
            }
        }
    }

    // ---- epilogue: agg = acc/l, LDS round-trip to A-layout, @W_lin^T, sigmoid
    unsigned short* aggl = ((unsigned short*)Plds) + w * 2176;  // reuse own P slice
    float invl[4];
    #pragma unroll
    for (int r = 0; r < 4; ++r) invl[r] = 1.f / l_keep[r];
    #pragma unroll
    for (int nt = 0; nt < 4; ++nt)
        #pragma unroll
        for (int r = 0; r < 4; ++r)   // row stride 72 ushort = 144B = 4*9 dw
            aggl[(q * 4 + r) * 72 + nt * 16 + i15] = f2bf(acc[nt][r] * invl[r]);

    f32x4 d2[4] = {};
    #pragma unroll
    for (int s = 0; s < 2; ++s) {
        bf16x8 af = *(const bf16x8*)&aggl[i15 * 72 + s * 32 + q * 8];
        #pragma unroll
        for (int nt = 0; nt < 4; ++nt) {
            const float* wp = Wlin + (size_t)(nt * 16 + i15) * C_ + s * 32 + q * 8;
            bf16x8 bfr;
            #pragma unroll
            for (int jj = 0; jj < 8; ++jj) bfr[jj] = (__bf16)wp[jj];
            d2[nt] = __builtin_amdgcn_mfma_f32_16x16x32_bf16(af, bfr, d2[nt], 0, 0, 0);
        }
    }
    float* orow = out + ((size_t)bp * N_ + ibase) * C_;
    #pragma unroll
    for (int nt = 0; nt < 4; ++nt)
        #pragma unroll
        for (int r = 0; r < 4; ++r)
            orow[(size_t)(q * 4 + r) * C_ + nt * 16 + i15] =
                1.f / (1.f + __expf(-d2[nt][r]));
}

extern "C" void kernel_launch(void* const* d_in, const int* in_sizes, int n_in,
                              void* d_out, int out_size, void* d_ws, size_t ws_size,
                              hipStream_t stream) {
    const float* x    = (const float*)d_in[0];
    const float* Ag   = (const float*)d_in[1];
    const float* Wemb = (const float*)d_in[2];
    const float* a1   = (const float*)d_in[3];
    const float* a2   = (const float*)d_in[4];
    const float* Wlin = (const float*)d_in[5];
    float* out  = (float*)d_out;
    float* outA = out + (size_t)BP_ * N_ * C_;   // tuple output #2: A passthrough

    float* s1g = (float*)d_ws;                   // 48*1024 f32
    float* s2g = s1g + BP_ * N_;                 // 48*1024 f32
    unsigned short* xT = (unsigned short*)(s2g + BP_ * N_);  // 48*64*1024 bf16 (6.3MB)

    dim3 grid(16, BP_);
    gat_pre<<<grid, dim3(256), 0, stream>>>(x, Wemb, a1, a2, s1g, s2g, xT);
    gat_main<<<grid, dim3(256), 0, stream>>>(Ag, xT, s1g, s2g, Wlin, out, outA);
}